// Round 1
// baseline (2932.239 us; speedup 1.0000x reference)
//
#include <hip/hip_runtime.h>

#define NFEAT 256
#define NHID  128

// ---------------------------------------------------------------------------
// 1) Spectral norm: one power iteration. sigma = ||W v||, v = normalize(W^T u).
//    Single block of 256 threads; writes 1/sigma to scal[0].
// ---------------------------------------------------------------------------
__global__ __launch_bounds__(256) void sigma_kernel(const float* __restrict__ W,
                                                    const float* __restrict__ u,
                                                    float* __restrict__ scal) {
    __shared__ float v[NHID];
    __shared__ float red[256];
    int tid = threadIdx.x;

    // v_raw[j] = sum_i W[i,j] * u[i]   (j = tid < 128)
    float t = 0.f;
    if (tid < NHID) {
        for (int i = 0; i < NFEAT; ++i) t += W[i * NHID + tid] * u[i];
    }
    red[tid] = (tid < NHID) ? t * t : 0.f;
    __syncthreads();
    for (int s = 128; s > 0; s >>= 1) {
        if (tid < s) red[tid] += red[tid + s];
        __syncthreads();
    }
    float nv = sqrtf(red[0]);
    float inv_nv = 1.f / (nv + 1e-12f);
    __syncthreads();
    if (tid < NHID) v[tid] = t * inv_nv;
    __syncthreads();

    // wv[i] = sum_j W[i,j] * v[j]   (i = tid, 256 rows)
    float wv = 0.f;
    for (int j = 0; j < NHID; ++j) wv += W[tid * NHID + j] * v[j];
    red[tid] = wv * wv;
    __syncthreads();
    for (int s = 128; s > 0; s >>= 1) {
        if (tid < s) red[tid] += red[tid + s];
        __syncthreads();
    }
    if (tid == 0) {
        float n2  = red[0];           // ||Wv||^2
        float nwv = sqrtf(n2);
        float sigma = n2 / (nwv + 1e-12f);   // == u2 . (W v) with the eps semantics
        scal[0] = 1.f / sigma;
    }
}

// ---------------------------------------------------------------------------
// 2) Degree: cnt[i] = 1 (self loop) + #incoming edges at i; then dinv = rsqrt.
// ---------------------------------------------------------------------------
__global__ void init_cnt_kernel(float* __restrict__ cnt, int n) {
    int i = blockIdx.x * 256 + threadIdx.x;
    if (i < n) cnt[i] = 1.f;
}

__global__ void count_kernel(const int* __restrict__ col, float* __restrict__ cnt, int e) {
    int i = blockIdx.x * 256 + threadIdx.x;
    if (i < e) atomicAdd(&cnt[col[i]], 1.f);
}

__global__ void dinv_kernel(const float* __restrict__ cnt, float* __restrict__ dinv, int n) {
    int i = blockIdx.x * 256 + threadIdx.x;
    if (i < n) dinv[i] = rsqrtf(cnt[i]);   // cnt >= 1 always
}

// ---------------------------------------------------------------------------
// 3) GEMM: xw[i,:] = dinv[i] * (1/sigma) * (x[i,:] @ W)
//    Block = 256 threads, 32 rows per block, fp32 vector ALU.
//    Thread (ty=tid>>5, tx=tid&31) computes rows ty*4..+3, cols tx*4..+3.
// ---------------------------------------------------------------------------
__global__ __launch_bounds__(256) void gemm_kernel(const float* __restrict__ x,
                                                   const float* __restrict__ W,
                                                   const float* __restrict__ dinv,
                                                   const float* __restrict__ scal,
                                                   float* __restrict__ xw) {
    __shared__ float xs[32][33];   // +1 pad
    int tid = threadIdx.x;
    int tx = tid & 31;             // col quad: cols tx*4 .. tx*4+3
    int ty = tid >> 5;             // 0..7 -> rows ty*4 .. ty*4+3
    int row0 = blockIdx.x * 32;

    float acc[4][4] = {};

    for (int k0 = 0; k0 < NFEAT; k0 += 32) {
        // cooperative load of x tile [32 rows][32 k]
        int lr = tid >> 3;             // 0..31
        int lk = (tid & 7) * 4;        // 0,4,...,28
        const float4 xv4 = *(const float4*)&x[(size_t)(row0 + lr) * NFEAT + k0 + lk];
        xs[lr][lk + 0] = xv4.x;
        xs[lr][lk + 1] = xv4.y;
        xs[lr][lk + 2] = xv4.z;
        xs[lr][lk + 3] = xv4.w;
        __syncthreads();

        for (int k = 0; k < 32; ++k) {
            const float4 wv = *(const float4*)&W[(size_t)(k0 + k) * NHID + tx * 4];
#pragma unroll
            for (int r = 0; r < 4; ++r) {
                float xv = xs[ty * 4 + r][k];
                acc[r][0] += xv * wv.x;
                acc[r][1] += xv * wv.y;
                acc[r][2] += xv * wv.z;
                acc[r][3] += xv * wv.w;
            }
        }
        __syncthreads();
    }

    float is = scal[0];
#pragma unroll
    for (int r = 0; r < 4; ++r) {
        int row = row0 + ty * 4 + r;
        float s = dinv[row] * is;
        float4 o;
        o.x = acc[r][0] * s;
        o.y = acc[r][1] * s;
        o.z = acc[r][2] * s;
        o.w = acc[r][3] * s;
        *(float4*)&xw[(size_t)row * NHID + tx * 4] = o;
    }
}

// ---------------------------------------------------------------------------
// 4) Scatter: out[col,:] += xw[row,:]  (atomic f32). 32 threads per edge,
//    each handling a float4 of the 128 features.
// ---------------------------------------------------------------------------
__global__ __launch_bounds__(256) void scatter_kernel(const int* __restrict__ erow,
                                                      const int* __restrict__ ecol,
                                                      const float* __restrict__ xw,
                                                      float* __restrict__ out, int e) {
    int idx = blockIdx.x * 256 + threadIdx.x;
    int eid = idx >> 5;
    if (eid >= e) return;
    int q = idx & 31;
    int r = erow[eid];
    int c = ecol[eid];
    const float4 v = *(const float4*)&xw[(size_t)r * NHID + q * 4];
    float* o = &out[(size_t)c * NHID + q * 4];
    atomicAdd(o + 0, v.x);
    atomicAdd(o + 1, v.y);
    atomicAdd(o + 2, v.z);
    atomicAdd(o + 3, v.w);
}

// ---------------------------------------------------------------------------
// 5) Finalize: out[i,:] = prelu( dinv[i]*(acc + xw[i,:]) + bias )
// ---------------------------------------------------------------------------
__global__ __launch_bounds__(256) void finalize_kernel(const float* __restrict__ xw,
                                                       const float* __restrict__ dinv,
                                                       const float* __restrict__ bias,
                                                       const float* __restrict__ pa,
                                                       float* __restrict__ out, int n) {
    int idx = blockIdx.x * 256 + threadIdx.x;
    int node = idx >> 5;
    if (node >= n) return;
    int q = idx & 31;
    size_t off = (size_t)node * NHID + q * 4;
    float4 a  = *(const float4*)&out[off];
    float4 xs = *(const float4*)&xw[off];
    float4 b  = *(const float4*)&bias[q * 4];
    float s = dinv[node];
    float alpha = pa[0];
    float4 o;
    o.x = s * (a.x + xs.x) + b.x;
    o.y = s * (a.y + xs.y) + b.y;
    o.z = s * (a.z + xs.z) + b.z;
    o.w = s * (a.w + xs.w) + b.w;
    o.x = o.x > 0.f ? o.x : alpha * o.x;
    o.y = o.y > 0.f ? o.y : alpha * o.y;
    o.z = o.z > 0.f ? o.z : alpha * o.z;
    o.w = o.w > 0.f ? o.w : alpha * o.w;
    *(float4*)&out[off] = o;
}

// ---------------------------------------------------------------------------
extern "C" void kernel_launch(void* const* d_in, const int* in_sizes, int n_in,
                              void* d_out, int out_size, void* d_ws, size_t ws_size,
                              hipStream_t stream) {
    const float* x    = (const float*)d_in[0];
    const int*   ei   = (const int*)d_in[1];   // int32 (JAX x64 disabled), [2,E] row-major
    const float* W    = (const float*)d_in[2];
    const float* bias = (const float*)d_in[3];
    const float* pa   = (const float*)d_in[4];
    const float* u    = (const float*)d_in[5];

    int n = in_sizes[0] / NFEAT;     // 100000
    int e = in_sizes[1] / 2;         // 1600000
    const int* erow = ei;            // sources
    const int* ecol = ei + e;        // targets

    float* out = (float*)d_out;
    char* ws = (char*)d_ws;
    // workspace layout
    float* scal = (float*)(ws);                         // 1 float
    float* cnt  = (float*)(ws + (1u << 20));            // n floats
    float* dinv = (float*)(ws + (2u << 20));            // n floats
    float* xw   = (float*)(ws + (4u << 20));            // n*128 floats (51.2 MB)

    // out accumulates atomically -> must start at zero every call
    hipMemsetAsync(d_out, 0, (size_t)out_size * sizeof(float), stream);

    sigma_kernel<<<1, 256, 0, stream>>>(W, u, scal);

    init_cnt_kernel<<<(n + 255) / 256, 256, 0, stream>>>(cnt, n);
    count_kernel<<<(e + 255) / 256, 256, 0, stream>>>(ecol, cnt, e);
    dinv_kernel<<<(n + 255) / 256, 256, 0, stream>>>(cnt, dinv, n);

    gemm_kernel<<<n / 32, 256, 0, stream>>>(x, W, dinv, scal, xw);

    long long sunits = (long long)e * 32;
    scatter_kernel<<<(int)((sunits + 255) / 256), 256, 0, stream>>>(erow, ecol, xw, out, e);

    long long funits = (long long)n * 32;
    finalize_kernel<<<(int)((funits + 255) / 256), 256, 0, stream>>>(xw, dinv, bias, pa, out, n);
}

// Round 2
// 454.635 us; speedup vs baseline: 6.4497x; 6.4497x over previous
//
#include <hip/hip_runtime.h>

#define NFEAT 256
#define NHID  128

// ---------------------------------------------------------------------------
// 1) Spectral norm: one power iteration. sigma = ||W v||, v = normalize(W^T u).
// ---------------------------------------------------------------------------
__global__ __launch_bounds__(256) void sigma_kernel(const float* __restrict__ W,
                                                    const float* __restrict__ u,
                                                    float* __restrict__ scal) {
    __shared__ float v[NHID];
    __shared__ float red[256];
    int tid = threadIdx.x;

    float t = 0.f;
    if (tid < NHID) {
        for (int i = 0; i < NFEAT; ++i) t += W[i * NHID + tid] * u[i];
    }
    red[tid] = (tid < NHID) ? t * t : 0.f;
    __syncthreads();
    for (int s = 128; s > 0; s >>= 1) {
        if (tid < s) red[tid] += red[tid + s];
        __syncthreads();
    }
    float nv = sqrtf(red[0]);
    float inv_nv = 1.f / (nv + 1e-12f);
    __syncthreads();
    if (tid < NHID) v[tid] = t * inv_nv;
    __syncthreads();

    float wv = 0.f;
    for (int j = 0; j < NHID; ++j) wv += W[tid * NHID + j] * v[j];
    red[tid] = wv * wv;
    __syncthreads();
    for (int s = 128; s > 0; s >>= 1) {
        if (tid < s) red[tid] += red[tid + s];
        __syncthreads();
    }
    if (tid == 0) {
        float n2  = red[0];
        float nwv = sqrtf(n2);
        float sigma = n2 / (nwv + 1e-12f);
        scal[0] = 1.f / sigma;
    }
}

// ---------------------------------------------------------------------------
// 2) Degree count (int) over destinations; dinv = rsqrt(cnt+1)  (+1 self loop)
// ---------------------------------------------------------------------------
__global__ void count_kernel(const int* __restrict__ col, int* __restrict__ cnt, int e) {
    int i = blockIdx.x * 256 + threadIdx.x;
    if (i < e) atomicAdd(&cnt[col[i]], 1);
}

__global__ void dinv_kernel(const int* __restrict__ cnt, float* __restrict__ dinv, int n) {
    int i = blockIdx.x * 256 + threadIdx.x;
    if (i < n) dinv[i] = rsqrtf((float)cnt[i] + 1.f);
}

// ---------------------------------------------------------------------------
// 3) Hierarchical exclusive scan of cnt -> base  (1024 elems per block)
// ---------------------------------------------------------------------------
__global__ __launch_bounds__(256) void scan_block_kernel(const int* __restrict__ cnt,
                                                         int* __restrict__ base,
                                                         int* __restrict__ bsum, int n) {
    __shared__ int ps[256];
    int blk = blockIdx.x, tid = threadIdx.x;
    int i0 = blk * 1024 + tid * 4;
    int a0 = 0, a1 = 0, a2 = 0, a3 = 0;
    if (i0 + 3 < n) {
        int4 v = *(const int4*)&cnt[i0];
        a0 = v.x; a1 = v.y; a2 = v.z; a3 = v.w;
    } else {
        if (i0     < n) a0 = cnt[i0];
        if (i0 + 1 < n) a1 = cnt[i0 + 1];
        if (i0 + 2 < n) a2 = cnt[i0 + 2];
        if (i0 + 3 < n) a3 = cnt[i0 + 3];
    }
    int tsum = a0 + a1 + a2 + a3;
    ps[tid] = tsum;
    __syncthreads();
    int val = tsum;
    for (int off = 1; off < 256; off <<= 1) {
        int t = (tid >= off) ? ps[tid - off] : 0;
        __syncthreads();
        val += t;
        ps[tid] = val;
        __syncthreads();
    }
    int excl = val - tsum;
    if (i0     < n) base[i0]     = excl;
    if (i0 + 1 < n) base[i0 + 1] = excl + a0;
    if (i0 + 2 < n) base[i0 + 2] = excl + a0 + a1;
    if (i0 + 3 < n) base[i0 + 3] = excl + a0 + a1 + a2;
    if (tid == 255) bsum[blk] = val;
}

__global__ __launch_bounds__(128) void scan_top_kernel(const int* __restrict__ bsum,
                                                       int* __restrict__ boff, int nb) {
    __shared__ int ps[128];
    int tid = threadIdx.x;
    int v = (tid < nb) ? bsum[tid] : 0;
    ps[tid] = v;
    __syncthreads();
    int val = v;
    for (int off = 1; off < 128; off <<= 1) {
        int t = (tid >= off) ? ps[tid - off] : 0;
        __syncthreads();
        val += t;
        ps[tid] = val;
        __syncthreads();
    }
    if (tid < nb) boff[tid] = val - v;
}

__global__ __launch_bounds__(256) void add_off_kernel(int* __restrict__ base,
                                                      int* __restrict__ fillc,
                                                      const int* __restrict__ boff, int n) {
    int blk = blockIdx.x, tid = threadIdx.x;
    int off = boff[blk];
    int i0 = blk * 1024 + tid * 4;
#pragma unroll
    for (int j = 0; j < 4; ++j) {
        int i = i0 + j;
        if (i < n) {
            int b = base[i] + off;
            base[i] = b;
            fillc[i] = b;
        }
    }
}

// ---------------------------------------------------------------------------
// 4) Bucket edges by destination: ebuf[pos] = source
// ---------------------------------------------------------------------------
__global__ void fill_kernel(const int* __restrict__ erow, const int* __restrict__ ecol,
                            int* __restrict__ fillc, int* __restrict__ ebuf, int e) {
    int i = blockIdx.x * 256 + threadIdx.x;
    if (i < e) {
        int c = ecol[i];
        int p = atomicAdd(&fillc[c], 1);
        ebuf[p] = erow[i];
    }
}

// ---------------------------------------------------------------------------
// 5) GEMM: xw[i,:] = dinv[i] * (1/sigma) * (x[i,:] @ W)
// ---------------------------------------------------------------------------
__global__ __launch_bounds__(256) void gemm_kernel(const float* __restrict__ x,
                                                   const float* __restrict__ W,
                                                   const float* __restrict__ dinv,
                                                   const float* __restrict__ scal,
                                                   float* __restrict__ xw) {
    __shared__ float xs[32][33];
    int tid = threadIdx.x;
    int tx = tid & 31;
    int ty = tid >> 5;
    int row0 = blockIdx.x * 32;

    float acc[4][4] = {};

    for (int k0 = 0; k0 < NFEAT; k0 += 32) {
        int lr = tid >> 3;
        int lk = (tid & 7) * 4;
        const float4 xv4 = *(const float4*)&x[(size_t)(row0 + lr) * NFEAT + k0 + lk];
        xs[lr][lk + 0] = xv4.x;
        xs[lr][lk + 1] = xv4.y;
        xs[lr][lk + 2] = xv4.z;
        xs[lr][lk + 3] = xv4.w;
        __syncthreads();

        for (int k = 0; k < 32; ++k) {
            const float4 wv = *(const float4*)&W[(size_t)(k0 + k) * NHID + tx * 4];
#pragma unroll
            for (int r = 0; r < 4; ++r) {
                float xv = xs[ty * 4 + r][k];
                acc[r][0] += xv * wv.x;
                acc[r][1] += xv * wv.y;
                acc[r][2] += xv * wv.z;
                acc[r][3] += xv * wv.w;
            }
        }
        __syncthreads();
    }

    float is = scal[0];
#pragma unroll
    for (int r = 0; r < 4; ++r) {
        int row = row0 + ty * 4 + r;
        float s = dinv[row] * is;
        float4 o;
        o.x = acc[r][0] * s;
        o.y = acc[r][1] * s;
        o.z = acc[r][2] * s;
        o.w = acc[r][3] * s;
        *(float4*)&xw[(size_t)row * NHID + tx * 4] = o;
    }
}

// ---------------------------------------------------------------------------
// 6) Gather + finalize: one wave per node. acc = xw[self] + sum_in xw[src];
//    out = prelu(dinv*acc + bias). 2 floats per lane (128 feats / 64 lanes).
// ---------------------------------------------------------------------------
__global__ __launch_bounds__(256) void gather_kernel(const float* __restrict__ xw,
                                                     const int* __restrict__ base,
                                                     const int* __restrict__ cnt,
                                                     const int* __restrict__ ebuf,
                                                     const float* __restrict__ dinv,
                                                     const float* __restrict__ bias,
                                                     const float* __restrict__ pa,
                                                     float* __restrict__ out, int n) {
    int lane = threadIdx.x & 63;
    int node = (blockIdx.x * 256 + threadIdx.x) >> 6;
    if (node >= n) return;
    const float2* xw2 = (const float2*)xw;

    int b = base[node];
    int deg = cnt[node];

    float2 s0 = xw2[(size_t)node * 64 + lane];   // self loop
    float ax = s0.x, ay = s0.y;

    int k = 0;
    for (; k + 4 <= deg; k += 4) {
        int r0 = ebuf[b + k + 0];
        int r1 = ebuf[b + k + 1];
        int r2 = ebuf[b + k + 2];
        int r3 = ebuf[b + k + 3];
        float2 v0 = xw2[(size_t)r0 * 64 + lane];
        float2 v1 = xw2[(size_t)r1 * 64 + lane];
        float2 v2 = xw2[(size_t)r2 * 64 + lane];
        float2 v3 = xw2[(size_t)r3 * 64 + lane];
        ax += v0.x + v1.x + v2.x + v3.x;
        ay += v0.y + v1.y + v2.y + v3.y;
    }
    for (; k < deg; ++k) {
        int r = ebuf[b + k];
        float2 v = xw2[(size_t)r * 64 + lane];
        ax += v.x;
        ay += v.y;
    }

    float s = dinv[node];
    float alpha = pa[0];
    float2 bb = ((const float2*)bias)[lane];
    float ox = s * ax + bb.x;
    float oy = s * ay + bb.y;
    ox = ox > 0.f ? ox : alpha * ox;
    oy = oy > 0.f ? oy : alpha * oy;
    ((float2*)out)[(size_t)node * 64 + lane] = make_float2(ox, oy);
}

// ---------------------------------------------------------------------------
extern "C" void kernel_launch(void* const* d_in, const int* in_sizes, int n_in,
                              void* d_out, int out_size, void* d_ws, size_t ws_size,
                              hipStream_t stream) {
    const float* x    = (const float*)d_in[0];
    const int*   ei   = (const int*)d_in[1];   // int32, [2,E] row-major
    const float* W    = (const float*)d_in[2];
    const float* bias = (const float*)d_in[3];
    const float* pa   = (const float*)d_in[4];
    const float* u    = (const float*)d_in[5];

    int n = in_sizes[0] / NFEAT;     // 100000
    int e = in_sizes[1] / 2;         // 1600000
    const int* erow = ei;            // sources
    const int* ecol = ei + e;        // targets

    float* out = (float*)d_out;
    char* ws = (char*)d_ws;
    // workspace layout (bytes)
    float* scal = (float*)(ws);                       // 4 B
    int*   cnt  = (int*)  (ws + 0x0010000);           // 64KB  : n ints (400KB)
    int*   base = (int*)  (ws + 0x0080000);           // 512KB : n ints
    int*   fillc= (int*)  (ws + 0x0100000);           // 1MB   : n ints
    int*   bsum = (int*)  (ws + 0x0180000);           // 1.5MB : ~98 ints
    int*   boff = (int*)  (ws + 0x0181000);           // +4KB
    float* dinv = (float*)(ws + 0x0190000);           // n floats (400KB)
    int*   ebuf = (int*)  (ws + 0x0200000);           // 2MB   : e ints (6.4MB)
    float* xw   = (float*)(ws + 0x0900000);           // 9MB   : n*128 floats (51.2MB)

    int nb = (n + 1023) / 1024;      // 98 scan blocks

    hipMemsetAsync(cnt, 0, (size_t)n * sizeof(int), stream);

    sigma_kernel<<<1, 256, 0, stream>>>(W, u, scal);
    count_kernel<<<(e + 255) / 256, 256, 0, stream>>>(ecol, cnt, e);
    dinv_kernel<<<(n + 255) / 256, 256, 0, stream>>>(cnt, dinv, n);
    scan_block_kernel<<<nb, 256, 0, stream>>>(cnt, base, bsum, n);
    scan_top_kernel<<<1, 128, 0, stream>>>(bsum, boff, nb);
    add_off_kernel<<<nb, 256, 0, stream>>>(base, fillc, boff, n);

    fill_kernel<<<(e + 255) / 256, 256, 0, stream>>>(erow, ecol, fillc, ebuf, e);

    gemm_kernel<<<n / 32, 256, 0, stream>>>(x, W, dinv, scal, xw);

    long long gunits = (long long)n * 64;
    gather_kernel<<<(int)((gunits + 255) / 256), 256, 0, stream>>>(
        xw, base, cnt, ebuf, dinv, bias, pa, out, n);
}

// Round 3
// 364.059 us; speedup vs baseline: 8.0543x; 1.2488x over previous
//
#include <hip/hip_runtime.h>

#define NFEAT 256
#define NHID  128

typedef __bf16 bf16x8 __attribute__((ext_vector_type(8)));
typedef float  f32x4  __attribute__((ext_vector_type(4)));

// ---------------------------------------------------------------------------
// 1) Spectral norm: one power iteration -> scal[0] = 1/sigma
// ---------------------------------------------------------------------------
__global__ __launch_bounds__(256) void sigma_kernel(const float* __restrict__ W,
                                                    const float* __restrict__ u,
                                                    float* __restrict__ scal) {
    __shared__ float v[NHID];
    __shared__ float red[256];
    int tid = threadIdx.x;

    float t = 0.f;
    if (tid < NHID) {
        for (int i = 0; i < NFEAT; ++i) t += W[i * NHID + tid] * u[i];
    }
    red[tid] = (tid < NHID) ? t * t : 0.f;
    __syncthreads();
    for (int s = 128; s > 0; s >>= 1) {
        if (tid < s) red[tid] += red[tid + s];
        __syncthreads();
    }
    float nv = sqrtf(red[0]);
    float inv_nv = 1.f / (nv + 1e-12f);
    __syncthreads();
    if (tid < NHID) v[tid] = t * inv_nv;
    __syncthreads();

    float wv = 0.f;
    for (int j = 0; j < NHID; ++j) wv += W[tid * NHID + j] * v[j];
    red[tid] = wv * wv;
    __syncthreads();
    for (int s = 128; s > 0; s >>= 1) {
        if (tid < s) red[tid] += red[tid + s];
        __syncthreads();
    }
    if (tid == 0) {
        float n2  = red[0];
        float nwv = sqrtf(n2);
        float sigma = n2 / (nwv + 1e-12f);
        scal[0] = 1.f / sigma;
    }
}

// ---------------------------------------------------------------------------
// 2) W^T in bf16, scaled by 1/sigma: WT[c][r] = bf16(W[r][c] / sigma)
// ---------------------------------------------------------------------------
__global__ __launch_bounds__(256) void wt_kernel(const float* __restrict__ W,
                                                 const float* __restrict__ scal,
                                                 __bf16* __restrict__ WT) {
    int idx = blockIdx.x * 256 + threadIdx.x;   // 32768 total
    int c = idx >> 8;     // 0..127
    int r = idx & 255;    // 0..255
    WT[c * NFEAT + r] = (__bf16)(W[r * NHID + c] * scal[0]);
}

// ---------------------------------------------------------------------------
// 3) Degree count over destinations; dinv = rsqrt(cnt+1)
// ---------------------------------------------------------------------------
__global__ void count_kernel(const int* __restrict__ col, int* __restrict__ cnt, int e) {
    int i = blockIdx.x * 256 + threadIdx.x;
    if (i < e) atomicAdd(&cnt[col[i]], 1);
}

__global__ void dinv_kernel(const int* __restrict__ cnt, float* __restrict__ dinv, int n) {
    int i = blockIdx.x * 256 + threadIdx.x;
    if (i < n) dinv[i] = rsqrtf((float)cnt[i] + 1.f);
}

// ---------------------------------------------------------------------------
// 4) Hierarchical exclusive scan of cnt -> base
// ---------------------------------------------------------------------------
__global__ __launch_bounds__(256) void scan_block_kernel(const int* __restrict__ cnt,
                                                         int* __restrict__ base,
                                                         int* __restrict__ bsum, int n) {
    __shared__ int ps[256];
    int blk = blockIdx.x, tid = threadIdx.x;
    int i0 = blk * 1024 + tid * 4;
    int a0 = 0, a1 = 0, a2 = 0, a3 = 0;
    if (i0 + 3 < n) {
        int4 v = *(const int4*)&cnt[i0];
        a0 = v.x; a1 = v.y; a2 = v.z; a3 = v.w;
    } else {
        if (i0     < n) a0 = cnt[i0];
        if (i0 + 1 < n) a1 = cnt[i0 + 1];
        if (i0 + 2 < n) a2 = cnt[i0 + 2];
        if (i0 + 3 < n) a3 = cnt[i0 + 3];
    }
    int tsum = a0 + a1 + a2 + a3;
    ps[tid] = tsum;
    __syncthreads();
    int val = tsum;
    for (int off = 1; off < 256; off <<= 1) {
        int t = (tid >= off) ? ps[tid - off] : 0;
        __syncthreads();
        val += t;
        ps[tid] = val;
        __syncthreads();
    }
    int excl = val - tsum;
    if (i0     < n) base[i0]     = excl;
    if (i0 + 1 < n) base[i0 + 1] = excl + a0;
    if (i0 + 2 < n) base[i0 + 2] = excl + a0 + a1;
    if (i0 + 3 < n) base[i0 + 3] = excl + a0 + a1 + a2;
    if (tid == 255) bsum[blk] = val;
}

__global__ __launch_bounds__(128) void scan_top_kernel(const int* __restrict__ bsum,
                                                       int* __restrict__ boff, int nb) {
    __shared__ int ps[128];
    int tid = threadIdx.x;
    int v = (tid < nb) ? bsum[tid] : 0;
    ps[tid] = v;
    __syncthreads();
    int val = v;
    for (int off = 1; off < 128; off <<= 1) {
        int t = (tid >= off) ? ps[tid - off] : 0;
        __syncthreads();
        val += t;
        ps[tid] = val;
        __syncthreads();
    }
    if (tid < nb) boff[tid] = val - v;
}

__global__ __launch_bounds__(256) void add_off_kernel(int* __restrict__ base,
                                                      int* __restrict__ fillc,
                                                      const int* __restrict__ boff, int n) {
    int blk = blockIdx.x, tid = threadIdx.x;
    int off = boff[blk];
    int i0 = blk * 1024 + tid * 4;
#pragma unroll
    for (int j = 0; j < 4; ++j) {
        int i = i0 + j;
        if (i < n) {
            int b = base[i] + off;
            base[i] = b;
            fillc[i] = b;
        }
    }
}

// ---------------------------------------------------------------------------
// 5) Bucket edges by destination: ebuf[pos] = source
// ---------------------------------------------------------------------------
__global__ void fill_kernel(const int* __restrict__ erow, const int* __restrict__ ecol,
                            int* __restrict__ fillc, int* __restrict__ ebuf, int e) {
    int i = blockIdx.x * 256 + threadIdx.x;
    if (i < e) {
        int c = ecol[i];
        int p = atomicAdd(&fillc[c], 1);
        ebuf[p] = erow[i];
    }
}

// ---------------------------------------------------------------------------
// 6) MFMA GEMM: xwb[i,:] = bf16( dinv[i] * (x[i,:] @ W^T_sn) )
//    4 waves/block, wave = 16 rows x 128 cols, K=256 in 8 steps of 32.
//    No LDS, no barriers. A: fp32 global load + cvt; B: bf16 from WT (L2).
// ---------------------------------------------------------------------------
__global__ __launch_bounds__(256) void gemm_mfma_kernel(const float* __restrict__ x,
                                                        const __bf16* __restrict__ WT,
                                                        const float* __restrict__ dinv,
                                                        __bf16* __restrict__ xwb, int nn) {
    int tid  = threadIdx.x;
    int lane = tid & 63;
    int w    = tid >> 6;                 // wave 0..3
    int row0 = blockIdx.x * 64 + w * 16;
    int rfrag = lane & 15;               // A-row / B-col within 16-tile
    int kg    = lane >> 4;               // 0..3 k-group
    int arow  = row0 + rfrag;
    if (arow >= nn) arow = nn - 1;       // clamp loads; stores predicated

    f32x4 acc[8] = {};

    const float* xrow = x + (size_t)arow * NFEAT;
#pragma unroll
    for (int ks = 0; ks < 8; ++ks) {
        int koff = ks * 32 + kg * 8;
        float4 lo = *(const float4*)&xrow[koff];
        float4 hi = *(const float4*)&xrow[koff + 4];
        bf16x8 af;
        af[0] = (__bf16)lo.x; af[1] = (__bf16)lo.y;
        af[2] = (__bf16)lo.z; af[3] = (__bf16)lo.w;
        af[4] = (__bf16)hi.x; af[5] = (__bf16)hi.y;
        af[6] = (__bf16)hi.z; af[7] = (__bf16)hi.w;
#pragma unroll
        for (int nt = 0; nt < 8; ++nt) {
            bf16x8 bf = *(const bf16x8*)&WT[(size_t)(nt * 16 + rfrag) * NFEAT + koff];
            acc[nt] = __builtin_amdgcn_mfma_f32_16x16x32_bf16(af, bf, acc[nt], 0, 0, 0);
        }
    }

    // C/D layout: col = lane&15, row = (lane>>4)*4 + reg
    int rbase = row0 + kg * 4;
#pragma unroll
    for (int reg = 0; reg < 4; ++reg) {
        int row = rbase + reg;
        if (row < nn) {
            float d = dinv[row];
#pragma unroll
            for (int nt = 0; nt < 8; ++nt) {
                xwb[(size_t)row * NHID + nt * 16 + rfrag] = (__bf16)(acc[nt][reg] * d);
            }
        }
    }
}

// ---------------------------------------------------------------------------
// 7) Gather + finalize: one wave per node; bf16 rows unpacked via shifts.
//    out = prelu(dinv*(xwb[self] + sum_in xwb[src]) + bias)
// ---------------------------------------------------------------------------
__global__ __launch_bounds__(256) void gather_kernel(const unsigned int* __restrict__ xb,
                                                     const int* __restrict__ base,
                                                     const int* __restrict__ cnt,
                                                     const int* __restrict__ ebuf,
                                                     const float* __restrict__ dinv,
                                                     const float* __restrict__ bias,
                                                     const float* __restrict__ pa,
                                                     float* __restrict__ out, int n) {
    int lane = threadIdx.x & 63;
    int node = (blockIdx.x * 256 + threadIdx.x) >> 6;
    if (node >= n) return;

    int b = base[node];
    int deg = cnt[node];

    unsigned int s0 = xb[(size_t)node * 64 + lane];  // cols 2*lane, 2*lane+1
    float ax = __uint_as_float(s0 << 16);
    float ay = __uint_as_float(s0 & 0xffff0000u);

    int k = 0;
    for (; k + 4 <= deg; k += 4) {
        int r0 = ebuf[b + k + 0];
        int r1 = ebuf[b + k + 1];
        int r2 = ebuf[b + k + 2];
        int r3 = ebuf[b + k + 3];
        unsigned int v0 = xb[(size_t)r0 * 64 + lane];
        unsigned int v1 = xb[(size_t)r1 * 64 + lane];
        unsigned int v2 = xb[(size_t)r2 * 64 + lane];
        unsigned int v3 = xb[(size_t)r3 * 64 + lane];
        ax += __uint_as_float(v0 << 16) + __uint_as_float(v1 << 16)
            + __uint_as_float(v2 << 16) + __uint_as_float(v3 << 16);
        ay += __uint_as_float(v0 & 0xffff0000u) + __uint_as_float(v1 & 0xffff0000u)
            + __uint_as_float(v2 & 0xffff0000u) + __uint_as_float(v3 & 0xffff0000u);
    }
    for (; k < deg; ++k) {
        int r = ebuf[b + k];
        unsigned int v = xb[(size_t)r * 64 + lane];
        ax += __uint_as_float(v << 16);
        ay += __uint_as_float(v & 0xffff0000u);
    }

    float s = dinv[node];
    float alpha = pa[0];
    float2 bb = ((const float2*)bias)[lane];
    float ox = s * ax + bb.x;
    float oy = s * ay + bb.y;
    ox = ox > 0.f ? ox : alpha * ox;
    oy = oy > 0.f ? oy : alpha * oy;
    ((float2*)out)[(size_t)node * 64 + lane] = make_float2(ox, oy);
}

// ---------------------------------------------------------------------------
extern "C" void kernel_launch(void* const* d_in, const int* in_sizes, int n_in,
                              void* d_out, int out_size, void* d_ws, size_t ws_size,
                              hipStream_t stream) {
    const float* x    = (const float*)d_in[0];
    const int*   ei   = (const int*)d_in[1];   // int32, [2,E] row-major
    const float* W    = (const float*)d_in[2];
    const float* bias = (const float*)d_in[3];
    const float* pa   = (const float*)d_in[4];
    const float* u    = (const float*)d_in[5];

    int n = in_sizes[0] / NFEAT;     // 100000
    int e = in_sizes[1] / 2;         // 1600000
    const int* erow = ei;            // sources
    const int* ecol = ei + e;        // targets

    float* out = (float*)d_out;
    char* ws = (char*)d_ws;
    // workspace layout (bytes)
    float*        scal = (float*)(ws);                  // 4 B
    int*          bsum = (int*)  (ws + 0x0001000);      // ~98 ints
    int*          boff = (int*)  (ws + 0x0002000);
    int*          cnt  = (int*)  (ws + 0x0100000);      // 400 KB
    int*          base = (int*)  (ws + 0x0200000);      // 400 KB
    int*          fillc= (int*)  (ws + 0x0300000);      // 400 KB
    float*        dinv = (float*)(ws + 0x0400000);      // 400 KB
    __bf16*       WT   = (__bf16*)(ws + 0x0500000);     // 64 KB
    int*          ebuf = (int*)  (ws + 0x0600000);      // 6.4 MB
    __bf16*       xwb  = (__bf16*)(ws + 0x0D00000);     // 25.6 MB

    int nb = (n + 1023) / 1024;      // 98 scan blocks

    hipMemsetAsync(cnt, 0, (size_t)n * sizeof(int), stream);

    sigma_kernel<<<1, 256, 0, stream>>>(W, u, scal);
    wt_kernel<<<(NFEAT * NHID) / 256, 256, 0, stream>>>(W, scal, WT);

    count_kernel<<<(e + 255) / 256, 256, 0, stream>>>(ecol, cnt, e);
    dinv_kernel<<<(n + 255) / 256, 256, 0, stream>>>(cnt, dinv, n);
    scan_block_kernel<<<nb, 256, 0, stream>>>(cnt, base, bsum, n);
    scan_top_kernel<<<1, 128, 0, stream>>>(bsum, boff, nb);
    add_off_kernel<<<nb, 256, 0, stream>>>(base, fillc, boff, n);

    fill_kernel<<<(e + 255) / 256, 256, 0, stream>>>(erow, ecol, fillc, ebuf, e);

    gemm_mfma_kernel<<<(n + 63) / 64, 256, 0, stream>>>(x, WT, dinv, xwb, n);

    long long gunits = (long long)n * 64;
    gather_kernel<<<(int)((gunits + 255) / 256), 256, 0, stream>>>(
        (const unsigned int*)xwb, base, cnt, ebuf, dinv, bias, pa, out, n);
}

// Round 4
// 195.553 us; speedup vs baseline: 14.9946x; 1.8617x over previous
//
#include <hip/hip_runtime.h>

#define NFEAT 256
#define NHID  128

#define NBK   391     // node buckets of 256 nodes (ceil(100000/256))
#define EPB   4096    // edges per block in hist/scatter passes
#define NBLK  391     // edge blocks (ceil(1600000/4096))

typedef __bf16 bf16x8 __attribute__((ext_vector_type(8)));
typedef float  f32x4  __attribute__((ext_vector_type(4)));

// ---------------------------------------------------------------------------
// 1) Spectral norm: one power iteration -> scal[0] = 1/sigma
// ---------------------------------------------------------------------------
__global__ __launch_bounds__(256) void sigma_kernel(const float* __restrict__ W,
                                                    const float* __restrict__ u,
                                                    float* __restrict__ scal) {
    __shared__ float v[NHID];
    __shared__ float red[256];
    int tid = threadIdx.x;

    float t = 0.f;
    if (tid < NHID) {
        for (int i = 0; i < NFEAT; ++i) t += W[i * NHID + tid] * u[i];
    }
    red[tid] = (tid < NHID) ? t * t : 0.f;
    __syncthreads();
    for (int s = 128; s > 0; s >>= 1) {
        if (tid < s) red[tid] += red[tid + s];
        __syncthreads();
    }
    float nv = sqrtf(red[0]);
    float inv_nv = 1.f / (nv + 1e-12f);
    __syncthreads();
    if (tid < NHID) v[tid] = t * inv_nv;
    __syncthreads();

    float wv = 0.f;
    for (int j = 0; j < NHID; ++j) wv += W[tid * NHID + j] * v[j];
    red[tid] = wv * wv;
    __syncthreads();
    for (int s = 128; s > 0; s >>= 1) {
        if (tid < s) red[tid] += red[tid + s];
        __syncthreads();
    }
    if (tid == 0) {
        float n2  = red[0];
        float nwv = sqrtf(n2);
        float sigma = n2 / (nwv + 1e-12f);
        scal[0] = 1.f / sigma;
    }
}

// ---------------------------------------------------------------------------
// 2) W^T in bf16, scaled by 1/sigma
// ---------------------------------------------------------------------------
__global__ __launch_bounds__(256) void wt_kernel(const float* __restrict__ W,
                                                 const float* __restrict__ scal,
                                                 __bf16* __restrict__ WT) {
    int idx = blockIdx.x * 256 + threadIdx.x;
    int c = idx >> 8;
    int r = idx & 255;
    WT[c * NFEAT + r] = (__bf16)(W[r * NHID + c] * scal[0]);
}

// ---------------------------------------------------------------------------
// 3) C1: per-block histogram over coarse buckets (bucket = dst >> 8)
//    blkhist layout: [bucket][block]  (bucket-major for the row scan)
// ---------------------------------------------------------------------------
__global__ __launch_bounds__(256) void hist_kernel(const int* __restrict__ ecol,
                                                   int* __restrict__ blkhist, int E) {
    __shared__ int hist[NBK];
    int tid = threadIdx.x, b = blockIdx.x;
    for (int k = tid; k < NBK; k += 256) hist[k] = 0;
    __syncthreads();
    int e0 = b * EPB;
#pragma unroll
    for (int j = 0; j < 16; ++j) {
        int idx = e0 + j * 256 + tid;
        if (idx < E) atomicAdd(&hist[ecol[idx] >> 8], 1);
    }
    __syncthreads();
    for (int k = tid; k < NBK; k += 256) blkhist[k * NBLK + b] = hist[k];
}

// ---------------------------------------------------------------------------
// 4) C3a: exclusive scan of each blkhist row (one wave per bucket) + row total
// ---------------------------------------------------------------------------
__global__ __launch_bounds__(256) void scan_rows_kernel(int* __restrict__ blkhist,
                                                        int* __restrict__ btot) {
    int k = blockIdx.x * 4 + (threadIdx.x >> 6);
    int lane = threadIdx.x & 63;
    if (k >= NBK) return;
    int carry = 0;
    for (int c0 = 0; c0 < NBLK; c0 += 64) {
        int b = c0 + lane;
        int v = (b < NBLK) ? blkhist[k * NBLK + b] : 0;
        int orig = v;
#pragma unroll
        for (int d = 1; d < 64; d <<= 1) {
            int t = __shfl_up(v, (unsigned)d, 64);
            if (lane >= d) v += t;
        }
        if (b < NBLK) blkhist[k * NBLK + b] = carry + v - orig;   // exclusive
        carry += __shfl(v, 63, 64);
    }
    if (lane == 0) btot[k] = carry;
}

// ---------------------------------------------------------------------------
// 5) C3b: exclusive scan of bucket totals -> bucket_base[0..NBK]
// ---------------------------------------------------------------------------
__global__ __launch_bounds__(512) void scan_buckets_kernel(const int* __restrict__ btot,
                                                           int* __restrict__ bbase) {
    __shared__ int s[512];
    int tid = threadIdx.x;
    int v = (tid < NBK) ? btot[tid] : 0;
    s[tid] = v;
    __syncthreads();
    int val = v;
    for (int off = 1; off < 512; off <<= 1) {
        int t = (tid >= off) ? s[tid - off] : 0;
        __syncthreads();
        val += t;
        s[tid] = val;
        __syncthreads();
    }
    if (tid <= NBK) bbase[tid] = val - v;   // tid==NBK (v=0) -> total
}

// ---------------------------------------------------------------------------
// 6) C4: coarse scatter — LDS-reorder 4096 edges by bucket, write segments
//    contiguously. rec = (dstLocal<<24) | src   (src < 2^17)
// ---------------------------------------------------------------------------
__global__ __launch_bounds__(512) void coarse_scatter_kernel(const int* __restrict__ erow,
                                                             const int* __restrict__ ecol,
                                                             const int* __restrict__ blkhist,
                                                             const int* __restrict__ bbase,
                                                             unsigned int* __restrict__ rbuf,
                                                             int E) {
    __shared__ unsigned int rec[EPB];
    __shared__ unsigned short bk[EPB];
    __shared__ int hist[NBK], sc[512], lbase[NBK], lfill[NBK], gb[NBK];
    int tid = threadIdx.x, b = blockIdx.x;
    for (int k = tid; k < NBK; k += 512) { hist[k] = 0; lfill[k] = 0; }
    __syncthreads();
    int e0 = b * EPB;
    unsigned int rv[8];
    int kv[8];
#pragma unroll
    for (int j = 0; j < 8; ++j) {
        int idx = e0 + j * 512 + tid;
        if (idx < E) {
            int c = ecol[idx];
            int s = erow[idx];
            int k = c >> 8;
            kv[j] = k;
            rv[j] = ((unsigned int)(c & 255) << 24) | (unsigned int)s;
            atomicAdd(&hist[k], 1);
        } else kv[j] = -1;
    }
    __syncthreads();
    int hv = (tid < NBK) ? hist[tid] : 0;
    sc[tid] = hv;
    __syncthreads();
    int val = hv;
    for (int off = 1; off < 512; off <<= 1) {
        int t = (tid >= off) ? sc[tid - off] : 0;
        __syncthreads();
        val += t;
        sc[tid] = val;
        __syncthreads();
    }
    if (tid < NBK) {
        lbase[tid] = val - hv;
        gb[tid] = bbase[tid] + blkhist[tid * NBLK + b];
    }
    __syncthreads();
#pragma unroll
    for (int j = 0; j < 8; ++j) {
        if (kv[j] >= 0) {
            int p = lbase[kv[j]] + atomicAdd(&lfill[kv[j]], 1);
            rec[p] = rv[j];
            bk[p] = (unsigned short)kv[j];
        }
    }
    __syncthreads();
    int nval = E - e0;
    if (nval > EPB) nval = EPB;
    for (int p = tid; p < nval; p += 512) {
        int k = bk[p];
        rbuf[gb[k] + (p - lbase[k])] = rec[p];
    }
}

// ---------------------------------------------------------------------------
// 7) F: fine pass — one block per bucket. LDS per-node counts + scan ->
//    exact CSR base, deg, dinv; then place sources into a 16KB local window.
// ---------------------------------------------------------------------------
__global__ __launch_bounds__(256) void fine_kernel(const unsigned int* __restrict__ rbuf,
                                                   const int* __restrict__ bbase,
                                                   int* __restrict__ base_g,
                                                   int* __restrict__ cnt_g,
                                                   float* __restrict__ dinv,
                                                   int* __restrict__ ebuf, int n) {
    __shared__ int cnt[256], lb[256], lf[256], sc[256];
    int tid = threadIdx.x, k = blockIdx.x;
    int seg0 = bbase[k], seg1 = bbase[k + 1];
    cnt[tid] = 0;
    lf[tid] = 0;
    __syncthreads();
    for (int j = seg0 + tid; j < seg1; j += 256)
        atomicAdd(&cnt[rbuf[j] >> 24], 1);
    __syncthreads();
    int cv = cnt[tid];
    sc[tid] = cv;
    __syncthreads();
    int val = cv;
    for (int off = 1; off < 256; off <<= 1) {
        int t = (tid >= off) ? sc[tid - off] : 0;
        __syncthreads();
        val += t;
        sc[tid] = val;
        __syncthreads();
    }
    lb[tid] = val - cv;   // exclusive
    __syncthreads();
    int node = k * 256 + tid;
    if (node < n) {
        base_g[node] = seg0 + lb[tid];
        cnt_g[node] = cv;
        dinv[node] = rsqrtf((float)cv + 1.f);
    }
    for (int j = seg0 + tid; j < seg1; j += 256) {
        unsigned int r = rbuf[j];
        int dl = r >> 24;
        int p = seg0 + lb[dl] + atomicAdd(&lf[dl], 1);
        ebuf[p] = (int)(r & 0xFFFFFFu);
    }
}

// ---------------------------------------------------------------------------
// 8) MFMA GEMM: xwb[i,:] = bf16( dinv[i] * (x[i,:] @ W^T_sn) )
// ---------------------------------------------------------------------------
__global__ __launch_bounds__(256) void gemm_mfma_kernel(const float* __restrict__ x,
                                                        const __bf16* __restrict__ WT,
                                                        const float* __restrict__ dinv,
                                                        __bf16* __restrict__ xwb, int nn) {
    int tid  = threadIdx.x;
    int lane = tid & 63;
    int w    = tid >> 6;
    int row0 = blockIdx.x * 64 + w * 16;
    int rfrag = lane & 15;
    int kg    = lane >> 4;
    int arow  = row0 + rfrag;
    if (arow >= nn) arow = nn - 1;

    f32x4 acc[8] = {};

    const float* xrow = x + (size_t)arow * NFEAT;
#pragma unroll
    for (int ks = 0; ks < 8; ++ks) {
        int koff = ks * 32 + kg * 8;
        float4 lo = *(const float4*)&xrow[koff];
        float4 hi = *(const float4*)&xrow[koff + 4];
        bf16x8 af;
        af[0] = (__bf16)lo.x; af[1] = (__bf16)lo.y;
        af[2] = (__bf16)lo.z; af[3] = (__bf16)lo.w;
        af[4] = (__bf16)hi.x; af[5] = (__bf16)hi.y;
        af[6] = (__bf16)hi.z; af[7] = (__bf16)hi.w;
#pragma unroll
        for (int nt = 0; nt < 8; ++nt) {
            bf16x8 bf = *(const bf16x8*)&WT[(size_t)(nt * 16 + rfrag) * NFEAT + koff];
            acc[nt] = __builtin_amdgcn_mfma_f32_16x16x32_bf16(af, bf, acc[nt], 0, 0, 0);
        }
    }

    int rbase = row0 + kg * 4;
#pragma unroll
    for (int reg = 0; reg < 4; ++reg) {
        int row = rbase + reg;
        if (row < nn) {
            float d = dinv[row];
#pragma unroll
            for (int nt = 0; nt < 8; ++nt) {
                xwb[(size_t)row * NHID + nt * 16 + rfrag] = (__bf16)(acc[nt][reg] * d);
            }
        }
    }
}

// ---------------------------------------------------------------------------
// 9) Gather + finalize: one wave per node; bf16 rows unpacked via shifts.
// ---------------------------------------------------------------------------
__global__ __launch_bounds__(256) void gather_kernel(const unsigned int* __restrict__ xb,
                                                     const int* __restrict__ base,
                                                     const int* __restrict__ cnt,
                                                     const int* __restrict__ ebuf,
                                                     const float* __restrict__ dinv,
                                                     const float* __restrict__ bias,
                                                     const float* __restrict__ pa,
                                                     float* __restrict__ out, int n) {
    int lane = threadIdx.x & 63;
    int node = (blockIdx.x * 256 + threadIdx.x) >> 6;
    if (node >= n) return;

    int b = base[node];
    int deg = cnt[node];

    unsigned int s0 = xb[(size_t)node * 64 + lane];
    float ax = __uint_as_float(s0 << 16);
    float ay = __uint_as_float(s0 & 0xffff0000u);

    int k = 0;
    for (; k + 4 <= deg; k += 4) {
        int r0 = ebuf[b + k + 0];
        int r1 = ebuf[b + k + 1];
        int r2 = ebuf[b + k + 2];
        int r3 = ebuf[b + k + 3];
        unsigned int v0 = xb[(size_t)r0 * 64 + lane];
        unsigned int v1 = xb[(size_t)r1 * 64 + lane];
        unsigned int v2 = xb[(size_t)r2 * 64 + lane];
        unsigned int v3 = xb[(size_t)r3 * 64 + lane];
        ax += __uint_as_float(v0 << 16) + __uint_as_float(v1 << 16)
            + __uint_as_float(v2 << 16) + __uint_as_float(v3 << 16);
        ay += __uint_as_float(v0 & 0xffff0000u) + __uint_as_float(v1 & 0xffff0000u)
            + __uint_as_float(v2 & 0xffff0000u) + __uint_as_float(v3 & 0xffff0000u);
    }
    for (; k < deg; ++k) {
        int r = ebuf[b + k];
        unsigned int v = xb[(size_t)r * 64 + lane];
        ax += __uint_as_float(v << 16);
        ay += __uint_as_float(v & 0xffff0000u);
    }

    float s = dinv[node];
    float alpha = pa[0];
    float2 bb = ((const float2*)bias)[lane];
    float ox = s * ax + bb.x;
    float oy = s * ay + bb.y;
    ox = ox > 0.f ? ox : alpha * ox;
    oy = oy > 0.f ? oy : alpha * oy;
    ((float2*)out)[(size_t)node * 64 + lane] = make_float2(ox, oy);
}

// ---------------------------------------------------------------------------
extern "C" void kernel_launch(void* const* d_in, const int* in_sizes, int n_in,
                              void* d_out, int out_size, void* d_ws, size_t ws_size,
                              hipStream_t stream) {
    const float* x    = (const float*)d_in[0];
    const int*   ei   = (const int*)d_in[1];   // int32, [2,E] row-major
    const float* W    = (const float*)d_in[2];
    const float* bias = (const float*)d_in[3];
    const float* pa   = (const float*)d_in[4];
    const float* u    = (const float*)d_in[5];

    int n = in_sizes[0] / NFEAT;     // 100000
    int e = in_sizes[1] / 2;         // 1600000
    const int* erow = ei;            // sources
    const int* ecol = ei + e;        // targets

    float* out = (float*)d_out;
    char* ws = (char*)d_ws;
    // workspace layout (bytes)
    float*        scal   = (float*)(ws);                    // 4 B
    int*          btot   = (int*)  (ws + 0x0001000);        // 392 ints
    int*          bbase  = (int*)  (ws + 0x0002000);        // 392 ints
    __bf16*       WT     = (__bf16*)(ws + 0x0010000);       // 64 KB
    int*          base_g = (int*)  (ws + 0x0100000);        // 400 KB
    int*          cnt_g  = (int*)  (ws + 0x0200000);        // 400 KB
    float*        dinv   = (float*)(ws + 0x0300000);        // 400 KB
    int*          blkhist= (int*)  (ws + 0x0400000);        // 611 KB
    unsigned int* rbuf   = (unsigned int*)(ws + 0x0500000); // 6.4 MB
    int*          ebuf   = (int*)  (ws + 0x0C00000);        // 6.4 MB
    __bf16*       xwb    = (__bf16*)(ws + 0x1300000);       // 25.6 MB

    sigma_kernel<<<1, 256, 0, stream>>>(W, u, scal);
    wt_kernel<<<(NFEAT * NHID) / 256, 256, 0, stream>>>(W, scal, WT);

    hist_kernel<<<NBLK, 256, 0, stream>>>(ecol, blkhist, e);
    scan_rows_kernel<<<(NBK + 3) / 4, 256, 0, stream>>>(blkhist, btot);
    scan_buckets_kernel<<<1, 512, 0, stream>>>(btot, bbase);
    coarse_scatter_kernel<<<NBLK, 512, 0, stream>>>(erow, ecol, blkhist, bbase, rbuf, e);
    fine_kernel<<<NBK, 256, 0, stream>>>(rbuf, bbase, base_g, cnt_g, dinv, ebuf, n);

    gemm_mfma_kernel<<<(n + 63) / 64, 256, 0, stream>>>(x, WT, dinv, xwb, n);

    long long gunits = (long long)n * 64;
    gather_kernel<<<(int)((gunits + 255) / 256), 256, 0, stream>>>(
        (const unsigned int*)xwb, base_g, cnt_g, ebuf, dinv, bias, pa, out, n);
}

// Round 5
// 185.543 us; speedup vs baseline: 15.8035x; 1.0539x over previous
//
#include <hip/hip_runtime.h>

#define NFEAT 256
#define NHID  128

#define NBK   391     // node buckets of 256 nodes (ceil(100000/256))
#define EPB   4096    // edges per block in hist/scatter passes
#define NBLK  391     // edge blocks (ceil(1600000/4096))

typedef __bf16 bf16x8 __attribute__((ext_vector_type(8)));
typedef __bf16 bf16x4 __attribute__((ext_vector_type(4)));
typedef float  f32x4  __attribute__((ext_vector_type(4)));

// ---------------------------------------------------------------------------
// 1) Spectral norm: one power iteration -> scal[0] = 1/sigma
// ---------------------------------------------------------------------------
__global__ __launch_bounds__(256) void sigma_kernel(const float* __restrict__ W,
                                                    const float* __restrict__ u,
                                                    float* __restrict__ scal) {
    __shared__ float v[NHID];
    __shared__ float red[256];
    int tid = threadIdx.x;

    float t = 0.f;
    if (tid < NHID) {
        for (int i = 0; i < NFEAT; ++i) t += W[i * NHID + tid] * u[i];
    }
    red[tid] = (tid < NHID) ? t * t : 0.f;
    __syncthreads();
    for (int s = 128; s > 0; s >>= 1) {
        if (tid < s) red[tid] += red[tid + s];
        __syncthreads();
    }
    float nv = sqrtf(red[0]);
    float inv_nv = 1.f / (nv + 1e-12f);
    __syncthreads();
    if (tid < NHID) v[tid] = t * inv_nv;
    __syncthreads();

    float wv = 0.f;
    for (int j = 0; j < NHID; ++j) wv += W[tid * NHID + j] * v[j];
    red[tid] = wv * wv;
    __syncthreads();
    for (int s = 128; s > 0; s >>= 1) {
        if (tid < s) red[tid] += red[tid + s];
        __syncthreads();
    }
    if (tid == 0) {
        float n2  = red[0];
        float nwv = sqrtf(n2);
        float sigma = n2 / (nwv + 1e-12f);
        scal[0] = 1.f / sigma;
    }
}

// ---------------------------------------------------------------------------
// 2) W^T in bf16, scaled by 1/sigma
// ---------------------------------------------------------------------------
__global__ __launch_bounds__(256) void wt_kernel(const float* __restrict__ W,
                                                 const float* __restrict__ scal,
                                                 __bf16* __restrict__ WT) {
    int idx = blockIdx.x * 256 + threadIdx.x;
    int c = idx >> 8;
    int r = idx & 255;
    WT[c * NFEAT + r] = (__bf16)(W[r * NHID + c] * scal[0]);
}

// ---------------------------------------------------------------------------
// 3) C1: per-block histogram over coarse buckets (bucket = dst >> 8)
// ---------------------------------------------------------------------------
__global__ __launch_bounds__(256) void hist_kernel(const int* __restrict__ ecol,
                                                   int* __restrict__ blkhist, int E) {
    __shared__ int hist[NBK];
    int tid = threadIdx.x, b = blockIdx.x;
    for (int k = tid; k < NBK; k += 256) hist[k] = 0;
    __syncthreads();
    int e0 = b * EPB;
#pragma unroll
    for (int j = 0; j < 16; ++j) {
        int idx = e0 + j * 256 + tid;
        if (idx < E) atomicAdd(&hist[ecol[idx] >> 8], 1);
    }
    __syncthreads();
    for (int k = tid; k < NBK; k += 256) blkhist[k * NBLK + b] = hist[k];
}

// ---------------------------------------------------------------------------
// 4) C3a: exclusive scan of each blkhist row (one wave per bucket) + row total
// ---------------------------------------------------------------------------
__global__ __launch_bounds__(256) void scan_rows_kernel(int* __restrict__ blkhist,
                                                        int* __restrict__ btot) {
    int k = blockIdx.x * 4 + (threadIdx.x >> 6);
    int lane = threadIdx.x & 63;
    if (k >= NBK) return;
    int carry = 0;
    for (int c0 = 0; c0 < NBLK; c0 += 64) {
        int b = c0 + lane;
        int v = (b < NBLK) ? blkhist[k * NBLK + b] : 0;
        int orig = v;
#pragma unroll
        for (int d = 1; d < 64; d <<= 1) {
            int t = __shfl_up(v, (unsigned)d, 64);
            if (lane >= d) v += t;
        }
        if (b < NBLK) blkhist[k * NBLK + b] = carry + v - orig;   // exclusive
        carry += __shfl(v, 63, 64);
    }
    if (lane == 0) btot[k] = carry;
}

// ---------------------------------------------------------------------------
// 5) C3b: exclusive scan of bucket totals -> bucket_base[0..NBK]
// ---------------------------------------------------------------------------
__global__ __launch_bounds__(512) void scan_buckets_kernel(const int* __restrict__ btot,
                                                           int* __restrict__ bbase) {
    __shared__ int s[512];
    int tid = threadIdx.x;
    int v = (tid < NBK) ? btot[tid] : 0;
    s[tid] = v;
    __syncthreads();
    int val = v;
    for (int off = 1; off < 512; off <<= 1) {
        int t = (tid >= off) ? s[tid - off] : 0;
        __syncthreads();
        val += t;
        s[tid] = val;
        __syncthreads();
    }
    if (tid <= NBK) bbase[tid] = val - v;   // tid==NBK (v=0) -> total
}

// ---------------------------------------------------------------------------
// 6) C4: coarse scatter — LDS-reorder 4096 edges by bucket, write segments
// ---------------------------------------------------------------------------
__global__ __launch_bounds__(512) void coarse_scatter_kernel(const int* __restrict__ erow,
                                                             const int* __restrict__ ecol,
                                                             const int* __restrict__ blkhist,
                                                             const int* __restrict__ bbase,
                                                             unsigned int* __restrict__ rbuf,
                                                             int E) {
    __shared__ unsigned int rec[EPB];
    __shared__ unsigned short bk[EPB];
    __shared__ int hist[NBK], sc[512], lbase[NBK], lfill[NBK], gb[NBK];
    int tid = threadIdx.x, b = blockIdx.x;
    for (int k = tid; k < NBK; k += 512) { hist[k] = 0; lfill[k] = 0; }
    __syncthreads();
    int e0 = b * EPB;
    unsigned int rv[8];
    int kv[8];
#pragma unroll
    for (int j = 0; j < 8; ++j) {
        int idx = e0 + j * 512 + tid;
        if (idx < E) {
            int c = ecol[idx];
            int s = erow[idx];
            int k = c >> 8;
            kv[j] = k;
            rv[j] = ((unsigned int)(c & 255) << 24) | (unsigned int)s;
            atomicAdd(&hist[k], 1);
        } else kv[j] = -1;
    }
    __syncthreads();
    int hv = (tid < NBK) ? hist[tid] : 0;
    sc[tid] = hv;
    __syncthreads();
    int val = hv;
    for (int off = 1; off < 512; off <<= 1) {
        int t = (tid >= off) ? sc[tid - off] : 0;
        __syncthreads();
        val += t;
        sc[tid] = val;
        __syncthreads();
    }
    if (tid < NBK) {
        lbase[tid] = val - hv;
        gb[tid] = bbase[tid] + blkhist[tid * NBLK + b];
    }
    __syncthreads();
#pragma unroll
    for (int j = 0; j < 8; ++j) {
        if (kv[j] >= 0) {
            int p = lbase[kv[j]] + atomicAdd(&lfill[kv[j]], 1);
            rec[p] = rv[j];
            bk[p] = (unsigned short)kv[j];
        }
    }
    __syncthreads();
    int nval = E - e0;
    if (nval > EPB) nval = EPB;
    for (int p = tid; p < nval; p += 512) {
        int k = bk[p];
        rbuf[gb[k] + (p - lbase[k])] = rec[p];
    }
}

// ---------------------------------------------------------------------------
// 7) F: fine pass — one block per bucket: per-node CSR base, deg, dinv, ebuf.
// ---------------------------------------------------------------------------
__global__ __launch_bounds__(256) void fine_kernel(const unsigned int* __restrict__ rbuf,
                                                   const int* __restrict__ bbase,
                                                   int* __restrict__ base_g,
                                                   int* __restrict__ cnt_g,
                                                   float* __restrict__ dinv,
                                                   int* __restrict__ ebuf, int n) {
    __shared__ int cnt[256], lb[256], lf[256], sc[256];
    int tid = threadIdx.x, k = blockIdx.x;
    int seg0 = bbase[k], seg1 = bbase[k + 1];
    cnt[tid] = 0;
    lf[tid] = 0;
    __syncthreads();
    for (int j = seg0 + tid; j < seg1; j += 256)
        atomicAdd(&cnt[rbuf[j] >> 24], 1);
    __syncthreads();
    int cv = cnt[tid];
    sc[tid] = cv;
    __syncthreads();
    int val = cv;
    for (int off = 1; off < 256; off <<= 1) {
        int t = (tid >= off) ? sc[tid - off] : 0;
        __syncthreads();
        val += t;
        sc[tid] = val;
        __syncthreads();
    }
    lb[tid] = val - cv;   // exclusive
    __syncthreads();
    int node = k * 256 + tid;
    if (node < n) {
        base_g[node] = seg0 + lb[tid];
        cnt_g[node] = cv;
        dinv[node] = rsqrtf((float)cv + 1.f);
    }
    for (int j = seg0 + tid; j < seg1; j += 256) {
        unsigned int r = rbuf[j];
        int dl = r >> 24;
        int p = seg0 + lb[dl] + atomicAdd(&lf[dl], 1);
        ebuf[p] = (int)(r & 0xFFFFFFu);
    }
}

// ---------------------------------------------------------------------------
// 8) MFMA GEMM (swapped-operand, 2 row-tiles/wave):
//    xwb[i,:] = bf16( dinv[i] * (x[i,:] @ W^T_sn) )
//    Wave = 32 rows x 128 cols. D-layout under swap: lane owns ONE x-row
//    (= lane&15 of each tile) and 4 consecutive output cols per fragment
//    -> packed 8B stores. B fragments feed both row-tiles (2x reuse).
// ---------------------------------------------------------------------------
__global__ __launch_bounds__(256) void gemm_mfma_kernel(const float* __restrict__ x,
                                                        const __bf16* __restrict__ WT,
                                                        const float* __restrict__ dinv,
                                                        __bf16* __restrict__ xwb, int nn) {
    int tid  = threadIdx.x;
    int lane = tid & 63;
    int w    = tid >> 6;                 // wave 0..3
    int rfrag = lane & 15;
    int kg    = lane >> 4;               // 0..3
    int row0 = blockIdx.x * 128 + w * 32;
    int r0 = row0 + rfrag;
    int r1 = r0 + 16;
    int lr0 = (r0 < nn) ? r0 : nn - 1;
    int lr1 = (r1 < nn) ? r1 : nn - 1;

    const float4* xr0 = (const float4*)(x + (size_t)lr0 * NFEAT);
    const float4* xr1 = (const float4*)(x + (size_t)lr1 * NFEAT);

    f32x4 acc0[8] = {};
    f32x4 acc1[8] = {};

    int idx0 = kg * 2;
    float4 a0 = xr0[idx0], b0 = xr0[idx0 + 1];
    float4 a1 = xr1[idx0], b1 = xr1[idx0 + 1];

#pragma unroll
    for (int ks = 0; ks < 8; ++ks) {
        bf16x8 af0, af1;
        af0[0] = (__bf16)a0.x; af0[1] = (__bf16)a0.y;
        af0[2] = (__bf16)a0.z; af0[3] = (__bf16)a0.w;
        af0[4] = (__bf16)b0.x; af0[5] = (__bf16)b0.y;
        af0[6] = (__bf16)b0.z; af0[7] = (__bf16)b0.w;
        af1[0] = (__bf16)a1.x; af1[1] = (__bf16)a1.y;
        af1[2] = (__bf16)a1.z; af1[3] = (__bf16)a1.w;
        af1[4] = (__bf16)b1.x; af1[5] = (__bf16)b1.y;
        af1[6] = (__bf16)b1.z; af1[7] = (__bf16)b1.w;

        if (ks < 7) {
            int nidx = (ks + 1) * 8 + kg * 2;
            a0 = xr0[nidx]; b0 = xr0[nidx + 1];
            a1 = xr1[nidx]; b1 = xr1[nidx + 1];
        }

        int koff = ks * 32 + kg * 8;
#pragma unroll
        for (int nt = 0; nt < 8; ++nt) {
            bf16x8 bf = *(const bf16x8*)&WT[(size_t)(nt * 16 + rfrag) * NFEAT + koff];
            acc0[nt] = __builtin_amdgcn_mfma_f32_16x16x32_bf16(bf, af0, acc0[nt], 0, 0, 0);
            acc1[nt] = __builtin_amdgcn_mfma_f32_16x16x32_bf16(bf, af1, acc1[nt], 0, 0, 0);
        }
    }

    // lane owns output row r0 (acc0) / r1 (acc1); cols nt*16 + kg*4 + reg
    if (r0 < nn) {
        float d = dinv[r0];
        __bf16* orow = xwb + (size_t)r0 * NHID + kg * 4;
#pragma unroll
        for (int nt = 0; nt < 8; ++nt) {
            bf16x4 v;
            v[0] = (__bf16)(acc0[nt][0] * d);
            v[1] = (__bf16)(acc0[nt][1] * d);
            v[2] = (__bf16)(acc0[nt][2] * d);
            v[3] = (__bf16)(acc0[nt][3] * d);
            *(bf16x4*)&orow[nt * 16] = v;
        }
    }
    if (r1 < nn) {
        float d = dinv[r1];
        __bf16* orow = xwb + (size_t)r1 * NHID + kg * 4;
#pragma unroll
        for (int nt = 0; nt < 8; ++nt) {
            bf16x4 v;
            v[0] = (__bf16)(acc1[nt][0] * d);
            v[1] = (__bf16)(acc1[nt][1] * d);
            v[2] = (__bf16)(acc1[nt][2] * d);
            v[3] = (__bf16)(acc1[nt][3] * d);
            *(bf16x4*)&orow[nt * 16] = v;
        }
    }
}

// ---------------------------------------------------------------------------
// 9) Gather + finalize: one wave per node; bf16 rows unpacked via shifts.
// ---------------------------------------------------------------------------
__global__ __launch_bounds__(256) void gather_kernel(const unsigned int* __restrict__ xb,
                                                     const int* __restrict__ base,
                                                     const int* __restrict__ cnt,
                                                     const int* __restrict__ ebuf,
                                                     const float* __restrict__ dinv,
                                                     const float* __restrict__ bias,
                                                     const float* __restrict__ pa,
                                                     float* __restrict__ out, int n) {
    int lane = threadIdx.x & 63;
    int node = (blockIdx.x * 256 + threadIdx.x) >> 6;
    if (node >= n) return;

    int b = base[node];
    int deg = cnt[node];

    unsigned int s0 = xb[(size_t)node * 64 + lane];
    float ax = __uint_as_float(s0 << 16);
    float ay = __uint_as_float(s0 & 0xffff0000u);

    int k = 0;
    for (; k + 4 <= deg; k += 4) {
        int r0 = ebuf[b + k + 0];
        int r1 = ebuf[b + k + 1];
        int r2 = ebuf[b + k + 2];
        int r3 = ebuf[b + k + 3];
        unsigned int v0 = xb[(size_t)r0 * 64 + lane];
        unsigned int v1 = xb[(size_t)r1 * 64 + lane];
        unsigned int v2 = xb[(size_t)r2 * 64 + lane];
        unsigned int v3 = xb[(size_t)r3 * 64 + lane];
        ax += __uint_as_float(v0 << 16) + __uint_as_float(v1 << 16)
            + __uint_as_float(v2 << 16) + __uint_as_float(v3 << 16);
        ay += __uint_as_float(v0 & 0xffff0000u) + __uint_as_float(v1 & 0xffff0000u)
            + __uint_as_float(v2 & 0xffff0000u) + __uint_as_float(v3 & 0xffff0000u);
    }
    for (; k < deg; ++k) {
        int r = ebuf[b + k];
        unsigned int v = xb[(size_t)r * 64 + lane];
        ax += __uint_as_float(v << 16);
        ay += __uint_as_float(v & 0xffff0000u);
    }

    float s = dinv[node];
    float alpha = pa[0];
    float2 bb = ((const float2*)bias)[lane];
    float ox = s * ax + bb.x;
    float oy = s * ay + bb.y;
    ox = ox > 0.f ? ox : alpha * ox;
    oy = oy > 0.f ? oy : alpha * oy;
    ((float2*)out)[(size_t)node * 64 + lane] = make_float2(ox, oy);
}

// ---------------------------------------------------------------------------
extern "C" void kernel_launch(void* const* d_in, const int* in_sizes, int n_in,
                              void* d_out, int out_size, void* d_ws, size_t ws_size,
                              hipStream_t stream) {
    const float* x    = (const float*)d_in[0];
    const int*   ei   = (const int*)d_in[1];   // int32, [2,E] row-major
    const float* W    = (const float*)d_in[2];
    const float* bias = (const float*)d_in[3];
    const float* pa   = (const float*)d_in[4];
    const float* u    = (const float*)d_in[5];

    int n = in_sizes[0] / NFEAT;     // 100000
    int e = in_sizes[1] / 2;         // 1600000
    const int* erow = ei;            // sources
    const int* ecol = ei + e;        // targets

    float* out = (float*)d_out;
    char* ws = (char*)d_ws;
    // workspace layout (bytes)
    float*        scal   = (float*)(ws);                    // 4 B
    int*          btot   = (int*)  (ws + 0x0001000);        // 392 ints
    int*          bbase  = (int*)  (ws + 0x0002000);        // 392 ints
    __bf16*       WT     = (__bf16*)(ws + 0x0010000);       // 64 KB
    int*          base_g = (int*)  (ws + 0x0100000);        // 400 KB
    int*          cnt_g  = (int*)  (ws + 0x0200000);        // 400 KB
    float*        dinv   = (float*)(ws + 0x0300000);        // 400 KB
    int*          blkhist= (int*)  (ws + 0x0400000);        // 611 KB
    unsigned int* rbuf   = (unsigned int*)(ws + 0x0500000); // 6.4 MB
    int*          ebuf   = (int*)  (ws + 0x0C00000);        // 6.4 MB
    __bf16*       xwb    = (__bf16*)(ws + 0x1300000);       // 25.6 MB

    sigma_kernel<<<1, 256, 0, stream>>>(W, u, scal);
    wt_kernel<<<(NFEAT * NHID) / 256, 256, 0, stream>>>(W, scal, WT);

    hist_kernel<<<NBLK, 256, 0, stream>>>(ecol, blkhist, e);
    scan_rows_kernel<<<(NBK + 3) / 4, 256, 0, stream>>>(blkhist, btot);
    scan_buckets_kernel<<<1, 512, 0, stream>>>(btot, bbase);
    coarse_scatter_kernel<<<NBLK, 512, 0, stream>>>(erow, ecol, blkhist, bbase, rbuf, e);
    fine_kernel<<<NBK, 256, 0, stream>>>(rbuf, bbase, base_g, cnt_g, dinv, ebuf, n);

    gemm_mfma_kernel<<<(n + 127) / 128, 256, 0, stream>>>(x, WT, dinv, xwb, n);

    long long gunits = (long long)n * 64;
    gather_kernel<<<(int)((gunits + 255) / 256), 256, 0, stream>>>(
        (const unsigned int*)xwb, base_g, cnt_g, ebuf, dinv, bias, pa, out, n);
}

// Round 6
// 174.671 us; speedup vs baseline: 16.7872x; 1.0622x over previous
//
#include <hip/hip_runtime.h>

#define NFEAT 256
#define NHID  128

#define NBK   391     // node buckets of 256 nodes (ceil(100000/256))
#define EPB   4096    // edges per block in hist/scatter passes
#define NBLK  391     // edge blocks (ceil(1600000/4096))

typedef __bf16 bf16x8 __attribute__((ext_vector_type(8)));
typedef __bf16 bf16x4 __attribute__((ext_vector_type(4)));
typedef float  f32x4  __attribute__((ext_vector_type(4)));

// ---------------------------------------------------------------------------
// 1) Spectral norm: one power iteration -> scal[0] = 1/sigma
// ---------------------------------------------------------------------------
__global__ __launch_bounds__(256) void sigma_kernel(const float* __restrict__ W,
                                                    const float* __restrict__ u,
                                                    float* __restrict__ scal) {
    __shared__ float v[NHID];
    __shared__ float red[256];
    int tid = threadIdx.x;

    float t = 0.f;
    if (tid < NHID) {
        for (int i = 0; i < NFEAT; ++i) t += W[i * NHID + tid] * u[i];
    }
    red[tid] = (tid < NHID) ? t * t : 0.f;
    __syncthreads();
    for (int s = 128; s > 0; s >>= 1) {
        if (tid < s) red[tid] += red[tid + s];
        __syncthreads();
    }
    float nv = sqrtf(red[0]);
    float inv_nv = 1.f / (nv + 1e-12f);
    __syncthreads();
    if (tid < NHID) v[tid] = t * inv_nv;
    __syncthreads();

    float wv = 0.f;
    for (int j = 0; j < NHID; ++j) wv += W[tid * NHID + j] * v[j];
    red[tid] = wv * wv;
    __syncthreads();
    for (int s = 128; s > 0; s >>= 1) {
        if (tid < s) red[tid] += red[tid + s];
        __syncthreads();
    }
    if (tid == 0) {
        float n2  = red[0];
        float nwv = sqrtf(n2);
        float sigma = n2 / (nwv + 1e-12f);
        scal[0] = 1.f / sigma;
    }
}

// ---------------------------------------------------------------------------
// 2) W^T in bf16, scaled by 1/sigma
// ---------------------------------------------------------------------------
__global__ __launch_bounds__(256) void wt_kernel(const float* __restrict__ W,
                                                 const float* __restrict__ scal,
                                                 __bf16* __restrict__ WT) {
    int idx = blockIdx.x * 256 + threadIdx.x;
    int c = idx >> 8;
    int r = idx & 255;
    WT[c * NFEAT + r] = (__bf16)(W[r * NHID + c] * scal[0]);
}

// ---------------------------------------------------------------------------
// 3) C1: per-block histogram over coarse buckets (bucket = dst >> 8)
// ---------------------------------------------------------------------------
__global__ __launch_bounds__(256) void hist_kernel(const int* __restrict__ ecol,
                                                   int* __restrict__ blkhist, int E) {
    __shared__ int hist[NBK];
    int tid = threadIdx.x, b = blockIdx.x;
    for (int k = tid; k < NBK; k += 256) hist[k] = 0;
    __syncthreads();
    int e0 = b * EPB;
#pragma unroll
    for (int j = 0; j < 16; ++j) {
        int idx = e0 + j * 256 + tid;
        if (idx < E) atomicAdd(&hist[ecol[idx] >> 8], 1);
    }
    __syncthreads();
    for (int k = tid; k < NBK; k += 256) blkhist[k * NBLK + b] = hist[k];
}

// ---------------------------------------------------------------------------
// 4) C3a: exclusive scan of each blkhist row (one wave per bucket) + row total
// ---------------------------------------------------------------------------
__global__ __launch_bounds__(256) void scan_rows_kernel(int* __restrict__ blkhist,
                                                        int* __restrict__ btot) {
    int k = blockIdx.x * 4 + (threadIdx.x >> 6);
    int lane = threadIdx.x & 63;
    if (k >= NBK) return;
    int carry = 0;
    for (int c0 = 0; c0 < NBLK; c0 += 64) {
        int b = c0 + lane;
        int v = (b < NBLK) ? blkhist[k * NBLK + b] : 0;
        int orig = v;
#pragma unroll
        for (int d = 1; d < 64; d <<= 1) {
            int t = __shfl_up(v, (unsigned)d, 64);
            if (lane >= d) v += t;
        }
        if (b < NBLK) blkhist[k * NBLK + b] = carry + v - orig;   // exclusive
        carry += __shfl(v, 63, 64);
    }
    if (lane == 0) btot[k] = carry;
}

// ---------------------------------------------------------------------------
// 5) C3b: exclusive scan of bucket totals -> bucket_base[0..NBK]
// ---------------------------------------------------------------------------
__global__ __launch_bounds__(512) void scan_buckets_kernel(const int* __restrict__ btot,
                                                           int* __restrict__ bbase) {
    __shared__ int s[512];
    int tid = threadIdx.x;
    int v = (tid < NBK) ? btot[tid] : 0;
    s[tid] = v;
    __syncthreads();
    int val = v;
    for (int off = 1; off < 512; off <<= 1) {
        int t = (tid >= off) ? s[tid - off] : 0;
        __syncthreads();
        val += t;
        s[tid] = val;
        __syncthreads();
    }
    if (tid <= NBK) bbase[tid] = val - v;   // tid==NBK (v=0) -> total
}

// ---------------------------------------------------------------------------
// 6) C4: coarse scatter — LDS-reorder 4096 edges by bucket, write segments
// ---------------------------------------------------------------------------
__global__ __launch_bounds__(512) void coarse_scatter_kernel(const int* __restrict__ erow,
                                                             const int* __restrict__ ecol,
                                                             const int* __restrict__ blkhist,
                                                             const int* __restrict__ bbase,
                                                             unsigned int* __restrict__ rbuf,
                                                             int E) {
    __shared__ unsigned int rec[EPB];
    __shared__ unsigned short bk[EPB];
    __shared__ int hist[NBK], sc[512], lbase[NBK], lfill[NBK], gb[NBK];
    int tid = threadIdx.x, b = blockIdx.x;
    for (int k = tid; k < NBK; k += 512) { hist[k] = 0; lfill[k] = 0; }
    __syncthreads();
    int e0 = b * EPB;
    unsigned int rv[8];
    int kv[8];
#pragma unroll
    for (int j = 0; j < 8; ++j) {
        int idx = e0 + j * 512 + tid;
        if (idx < E) {
            int c = ecol[idx];
            int s = erow[idx];
            int k = c >> 8;
            kv[j] = k;
            rv[j] = ((unsigned int)(c & 255) << 24) | (unsigned int)s;
            atomicAdd(&hist[k], 1);
        } else kv[j] = -1;
    }
    __syncthreads();
    int hv = (tid < NBK) ? hist[tid] : 0;
    sc[tid] = hv;
    __syncthreads();
    int val = hv;
    for (int off = 1; off < 512; off <<= 1) {
        int t = (tid >= off) ? sc[tid - off] : 0;
        __syncthreads();
        val += t;
        sc[tid] = val;
        __syncthreads();
    }
    if (tid < NBK) {
        lbase[tid] = val - hv;
        gb[tid] = bbase[tid] + blkhist[tid * NBLK + b];
    }
    __syncthreads();
#pragma unroll
    for (int j = 0; j < 8; ++j) {
        if (kv[j] >= 0) {
            int p = lbase[kv[j]] + atomicAdd(&lfill[kv[j]], 1);
            rec[p] = rv[j];
            bk[p] = (unsigned short)kv[j];
        }
    }
    __syncthreads();
    int nval = E - e0;
    if (nval > EPB) nval = EPB;
    for (int p = tid; p < nval; p += 512) {
        int k = bk[p];
        rbuf[gb[k] + (p - lbase[k])] = rec[p];
    }
}

// ---------------------------------------------------------------------------
// 7) F: fine pass — one block per bucket: per-node CSR base, deg, dinv, ebuf.
// ---------------------------------------------------------------------------
__global__ __launch_bounds__(256) void fine_kernel(const unsigned int* __restrict__ rbuf,
                                                   const int* __restrict__ bbase,
                                                   int* __restrict__ base_g,
                                                   int* __restrict__ cnt_g,
                                                   float* __restrict__ dinv,
                                                   int* __restrict__ ebuf, int n) {
    __shared__ int cnt[256], lb[256], lf[256], sc[256];
    int tid = threadIdx.x, k = blockIdx.x;
    int seg0 = bbase[k], seg1 = bbase[k + 1];
    cnt[tid] = 0;
    lf[tid] = 0;
    __syncthreads();
    for (int j = seg0 + tid; j < seg1; j += 256)
        atomicAdd(&cnt[rbuf[j] >> 24], 1);
    __syncthreads();
    int cv = cnt[tid];
    sc[tid] = cv;
    __syncthreads();
    int val = cv;
    for (int off = 1; off < 256; off <<= 1) {
        int t = (tid >= off) ? sc[tid - off] : 0;
        __syncthreads();
        val += t;
        sc[tid] = val;
        __syncthreads();
    }
    lb[tid] = val - cv;   // exclusive
    __syncthreads();
    int node = k * 256 + tid;
    if (node < n) {
        base_g[node] = seg0 + lb[tid];
        cnt_g[node] = cv;
        dinv[node] = rsqrtf((float)cv + 1.f);
    }
    for (int j = seg0 + tid; j < seg1; j += 256) {
        unsigned int r = rbuf[j];
        int dl = r >> 24;
        int p = seg0 + lb[dl] + atomicAdd(&lf[dl], 1);
        ebuf[p] = (int)(r & 0xFFFFFFu);
    }
}

// ---------------------------------------------------------------------------
// 8) MFMA GEMM v3 (swapped-operand, 2 row-chains, col-split waves):
//    wave = 32 rows x 64 cols  ->  block(256) = 64 rows x 128 cols.
//    Grid 1563 blocks -> ~24 waves/CU occupancy AND dual A-chain ILP.
// ---------------------------------------------------------------------------
__global__ __launch_bounds__(256) void gemm_mfma_kernel(const float* __restrict__ x,
                                                        const __bf16* __restrict__ WT,
                                                        const float* __restrict__ dinv,
                                                        __bf16* __restrict__ xwb, int nn) {
    int tid  = threadIdx.x;
    int lane = tid & 63;
    int w    = tid >> 6;                 // wave 0..3
    int rfrag = lane & 15;
    int kg    = lane >> 4;               // 0..3
    int row0 = blockIdx.x * 64 + (w & 1) * 32;
    int col0 = (w >> 1) * 64;            // 0 or 64
    int r0 = row0 + rfrag;
    int r1 = r0 + 16;
    int lr0 = (r0 < nn) ? r0 : nn - 1;
    int lr1 = (r1 < nn) ? r1 : nn - 1;

    const float4* xr0 = (const float4*)(x + (size_t)lr0 * NFEAT);
    const float4* xr1 = (const float4*)(x + (size_t)lr1 * NFEAT);

    f32x4 acc0[4] = {};
    f32x4 acc1[4] = {};

    int idx0 = kg * 2;
    float4 a0 = xr0[idx0], b0 = xr0[idx0 + 1];
    float4 a1 = xr1[idx0], b1 = xr1[idx0 + 1];

#pragma unroll
    for (int ks = 0; ks < 8; ++ks) {
        bf16x8 af0, af1;
        af0[0] = (__bf16)a0.x; af0[1] = (__bf16)a0.y;
        af0[2] = (__bf16)a0.z; af0[3] = (__bf16)a0.w;
        af0[4] = (__bf16)b0.x; af0[5] = (__bf16)b0.y;
        af0[6] = (__bf16)b0.z; af0[7] = (__bf16)b0.w;
        af1[0] = (__bf16)a1.x; af1[1] = (__bf16)a1.y;
        af1[2] = (__bf16)a1.z; af1[3] = (__bf16)a1.w;
        af1[4] = (__bf16)b1.x; af1[5] = (__bf16)b1.y;
        af1[6] = (__bf16)b1.z; af1[7] = (__bf16)b1.w;

        if (ks < 7) {
            int nidx = (ks + 1) * 8 + kg * 2;
            a0 = xr0[nidx]; b0 = xr0[nidx + 1];
            a1 = xr1[nidx]; b1 = xr1[nidx + 1];
        }

        int koff = ks * 32 + kg * 8;
#pragma unroll
        for (int nt = 0; nt < 4; ++nt) {
            bf16x8 bf = *(const bf16x8*)&WT[(size_t)(col0 + nt * 16 + rfrag) * NFEAT + koff];
            acc0[nt] = __builtin_amdgcn_mfma_f32_16x16x32_bf16(bf, af0, acc0[nt], 0, 0, 0);
            acc1[nt] = __builtin_amdgcn_mfma_f32_16x16x32_bf16(bf, af1, acc1[nt], 0, 0, 0);
        }
    }

    // lane owns output row r0 (acc0) / r1 (acc1); cols col0 + nt*16 + kg*4 + reg
    if (r0 < nn) {
        float d = dinv[r0];
        __bf16* orow = xwb + (size_t)r0 * NHID + col0 + kg * 4;
#pragma unroll
        for (int nt = 0; nt < 4; ++nt) {
            bf16x4 v;
            v[0] = (__bf16)(acc0[nt][0] * d);
            v[1] = (__bf16)(acc0[nt][1] * d);
            v[2] = (__bf16)(acc0[nt][2] * d);
            v[3] = (__bf16)(acc0[nt][3] * d);
            *(bf16x4*)&orow[nt * 16] = v;
        }
    }
    if (r1 < nn) {
        float d = dinv[r1];
        __bf16* orow = xwb + (size_t)r1 * NHID + col0 + kg * 4;
#pragma unroll
        for (int nt = 0; nt < 4; ++nt) {
            bf16x4 v;
            v[0] = (__bf16)(acc1[nt][0] * d);
            v[1] = (__bf16)(acc1[nt][1] * d);
            v[2] = (__bf16)(acc1[nt][2] * d);
            v[3] = (__bf16)(acc1[nt][3] * d);
            *(bf16x4*)&orow[nt * 16] = v;
        }
    }
}

// ---------------------------------------------------------------------------
// 9) Gather + finalize: HALF-WAVE per node (32 lanes x 8B = 256B row read).
//    Two independent chains per wave -> 8 outstanding row loads at unroll 4.
// ---------------------------------------------------------------------------
__global__ __launch_bounds__(256) void gather_kernel(const uint2* __restrict__ xb2,
                                                     const int* __restrict__ base,
                                                     const int* __restrict__ cnt,
                                                     const int* __restrict__ ebuf,
                                                     const float* __restrict__ dinv,
                                                     const float* __restrict__ bias,
                                                     const float* __restrict__ pa,
                                                     float* __restrict__ out, int n) {
    int tid = threadIdx.x;
    int sub = tid & 31;                               // sublane in half-wave
    int node = (blockIdx.x * 256 + tid) >> 5;         // one node per 32 lanes
    if (node >= n) return;

    int b = base[node];
    int deg = cnt[node];

    // self loop: row node, bf16 cols sub*4 .. sub*4+3
    uint2 s0 = xb2[(size_t)node * 32 + sub];
    float a0 = __uint_as_float(s0.x << 16);
    float a1 = __uint_as_float(s0.x & 0xffff0000u);
    float a2 = __uint_as_float(s0.y << 16);
    float a3 = __uint_as_float(s0.y & 0xffff0000u);

    int k = 0;
    for (; k + 4 <= deg; k += 4) {
        int r0 = ebuf[b + k + 0];
        int r1 = ebuf[b + k + 1];
        int r2 = ebuf[b + k + 2];
        int r3 = ebuf[b + k + 3];
        uint2 v0 = xb2[(size_t)r0 * 32 + sub];
        uint2 v1 = xb2[(size_t)r1 * 32 + sub];
        uint2 v2 = xb2[(size_t)r2 * 32 + sub];
        uint2 v3 = xb2[(size_t)r3 * 32 + sub];
        a0 += __uint_as_float(v0.x << 16) + __uint_as_float(v1.x << 16)
            + __uint_as_float(v2.x << 16) + __uint_as_float(v3.x << 16);
        a1 += __uint_as_float(v0.x & 0xffff0000u) + __uint_as_float(v1.x & 0xffff0000u)
            + __uint_as_float(v2.x & 0xffff0000u) + __uint_as_float(v3.x & 0xffff0000u);
        a2 += __uint_as_float(v0.y << 16) + __uint_as_float(v1.y << 16)
            + __uint_as_float(v2.y << 16) + __uint_as_float(v3.y << 16);
        a3 += __uint_as_float(v0.y & 0xffff0000u) + __uint_as_float(v1.y & 0xffff0000u)
            + __uint_as_float(v2.y & 0xffff0000u) + __uint_as_float(v3.y & 0xffff0000u);
    }
    for (; k < deg; ++k) {
        int r = ebuf[b + k];
        uint2 v = xb2[(size_t)r * 32 + sub];
        a0 += __uint_as_float(v.x << 16);
        a1 += __uint_as_float(v.x & 0xffff0000u);
        a2 += __uint_as_float(v.y << 16);
        a3 += __uint_as_float(v.y & 0xffff0000u);
    }

    float s = dinv[node];
    float alpha = pa[0];
    float4 bb = ((const float4*)bias)[sub];
    float o0 = s * a0 + bb.x;
    float o1 = s * a1 + bb.y;
    float o2 = s * a2 + bb.z;
    float o3 = s * a3 + bb.w;
    o0 = o0 > 0.f ? o0 : alpha * o0;
    o1 = o1 > 0.f ? o1 : alpha * o1;
    o2 = o2 > 0.f ? o2 : alpha * o2;
    o3 = o3 > 0.f ? o3 : alpha * o3;
    ((float4*)out)[(size_t)node * 32 + sub] = make_float4(o0, o1, o2, o3);
}

// ---------------------------------------------------------------------------
extern "C" void kernel_launch(void* const* d_in, const int* in_sizes, int n_in,
                              void* d_out, int out_size, void* d_ws, size_t ws_size,
                              hipStream_t stream) {
    const float* x    = (const float*)d_in[0];
    const int*   ei   = (const int*)d_in[1];   // int32, [2,E] row-major
    const float* W    = (const float*)d_in[2];
    const float* bias = (const float*)d_in[3];
    const float* pa   = (const float*)d_in[4];
    const float* u    = (const float*)d_in[5];

    int n = in_sizes[0] / NFEAT;     // 100000
    int e = in_sizes[1] / 2;         // 1600000
    const int* erow = ei;            // sources
    const int* ecol = ei + e;        // targets

    float* out = (float*)d_out;
    char* ws = (char*)d_ws;
    // workspace layout (bytes)
    float*        scal   = (float*)(ws);                    // 4 B
    int*          btot   = (int*)  (ws + 0x0001000);        // 392 ints
    int*          bbase  = (int*)  (ws + 0x0002000);        // 392 ints
    __bf16*       WT     = (__bf16*)(ws + 0x0010000);       // 64 KB
    int*          base_g = (int*)  (ws + 0x0100000);        // 400 KB
    int*          cnt_g  = (int*)  (ws + 0x0200000);        // 400 KB
    float*        dinv   = (float*)(ws + 0x0300000);        // 400 KB
    int*          blkhist= (int*)  (ws + 0x0400000);        // 611 KB
    unsigned int* rbuf   = (unsigned int*)(ws + 0x0500000); // 6.4 MB
    int*          ebuf   = (int*)  (ws + 0x0C00000);        // 6.4 MB
    __bf16*       xwb    = (__bf16*)(ws + 0x1300000);       // 25.6 MB

    sigma_kernel<<<1, 256, 0, stream>>>(W, u, scal);
    wt_kernel<<<(NFEAT * NHID) / 256, 256, 0, stream>>>(W, scal, WT);

    hist_kernel<<<NBLK, 256, 0, stream>>>(ecol, blkhist, e);
    scan_rows_kernel<<<(NBK + 3) / 4, 256, 0, stream>>>(blkhist, btot);
    scan_buckets_kernel<<<1, 512, 0, stream>>>(btot, bbase);
    coarse_scatter_kernel<<<NBLK, 512, 0, stream>>>(erow, ecol, blkhist, bbase, rbuf, e);
    fine_kernel<<<NBK, 256, 0, stream>>>(rbuf, bbase, base_g, cnt_g, dinv, ebuf, n);

    gemm_mfma_kernel<<<(n + 63) / 64, 256, 0, stream>>>(x, WT, dinv, xwb, n);

    long long gunits = (long long)n * 32;
    gather_kernel<<<(int)((gunits + 255) / 256), 256, 0, stream>>>(
        (const uint2*)xwb, base_g, cnt_g, ebuf, dinv, bias, pa, out, n);
}